// Round 8
// baseline (72.234 us; speedup 1.0000x reference)
//
#include <hip/hip_runtime.h>
#include <math.h>

// FeatureLabelLoss: features (B,C,D) f32, embeddings (C,D) f32, labels (B,C) f32
// -> scalar f32 loss.  BW-bound on the 327.7 MB features stream.
//
// Lessons so far:
//  R2: NO per-block __threadfence (buffer_wbl2 serializes the chip).
//  R5: NO same-address global atomic hammering (+79 us for 5000 fp64 adds).
//  R6: tail/balance is NOT the limiter (tail-free grid == R1 == 65.3 us).
//      Main kernel reads at ~5.7 TB/s vs ~6.9 TB/s contiguous-fill ceiling.
//  R4 regression re-diagnosed: launch_bounds-forced VGPR squeeze (spills) +
//      per-row HBM emb re-reads -- NOT contiguity itself.
//
// R7 single structural change: CONTIGUOUS feature streaming.
//  - wave = (b, 10 consecutive c's) -> 20 KB contiguous read.
//  - block = 4 waves (4 b's, same c-span); emb rows staged once to LDS
//    (20 KB tile), inv_ne computed cooperatively once per block.
//  - blk = s*8+bg -> XCD k owns b-group k, walks c linearly (clean streams).
//  - natural VGPR (no launch_bounds floor), ~7 blocks/CU by LDS.
//  - proven two-kernel finish (partial[] + tiny reduce).

typedef float f32x4 __attribute__((ext_vector_type(4)));

constexpr int B = 32;
constexpr int C = 5000;
constexpr int D = 512;                    // 512 floats = 2 f32x4 per lane
constexpr int NROWS = B * C;              // 160000
constexpr float EPS_LOG = 1e-6f;

constexpr int SPAN = 10;                  // c's per wave (20 KB contiguous)
constexpr int NSPAN = C / SPAN;           // 500
constexpr int WPB = 4;                    // waves (= b's) per block
constexpr int THREADS = WPB * 64;         // 256
constexpr int BGROUPS = B / WPB;          // 8
constexpr int NBLOCKS = NSPAN * BGROUPS;  // 4000

__global__ __launch_bounds__(THREADS) void fll_main(
    const float* __restrict__ feat,
    const float* __restrict__ emb,
    const float* __restrict__ labels,
    float* __restrict__ partial)
{
    __shared__ float tile[SPAN * D];      // 20 KB emb tile
    __shared__ float inv_ne[SPAN];
    __shared__ float wsum[WPB];

    const int t    = threadIdx.x;
    const int lane = t & 63;
    const int wid  = t >> 6;
    const int bg   = blockIdx.x & 7;      // XCD round-robin -> one b-group/XCD
    const int s    = blockIdx.x >> 3;     // c-span index, walks linearly
    const int b    = bg * WPB + wid;
    const int c0   = s * SPAN;

    // ---- stage emb tile: 1280 float4, 5 per thread, fully coalesced ----
    const f32x4* esrc = reinterpret_cast<const f32x4*>(emb + (size_t)c0 * D);
    f32x4* tl4 = reinterpret_cast<f32x4*>(tile);
    #pragma unroll
    for (int k = 0; k < (SPAN * D / 4) / THREADS; ++k)
        tl4[t + k * THREADS] = esrc[t + k * THREADS];
    __syncthreads();

    // ---- per-row inv_ne, computed once per block (wave wid does r=wid,wid+4,...)
    for (int r = wid; r < SPAN; r += WPB) {
        const f32x4 a0 = tl4[r * (D / 4) + lane];
        const f32x4 a1 = tl4[r * (D / 4) + lane + 64];
        float ss = a0.x * a0.x + a0.y * a0.y + a0.z * a0.z + a0.w * a0.w
                 + a1.x * a1.x + a1.y * a1.y + a1.z * a1.z + a1.w * a1.w;
        #pragma unroll
        for (int off = 32; off > 0; off >>= 1) ss += __shfl_xor(ss, off, 64);
        if (lane == 0) inv_ne[r] = 1.0f / sqrtf(ss);
    }
    __syncthreads();

    // ---- contiguous feature stream: 10 rows x 2 KB, one b per wave ----
    const float* fbase = feat + ((size_t)b * C + c0) * D;
    const float* lb    = labels + (size_t)b * C + c0;
    float wacc = 0.0f;   // identical across lanes of the wave

    #pragma unroll 2
    for (int r = 0; r < SPAN; ++r) {
        const f32x4* fr = reinterpret_cast<const f32x4*>(fbase + (size_t)r * D);
        const f32x4 f0 = fr[lane];
        const f32x4 f1 = fr[lane + 64];
        const f32x4 e0 = tl4[r * (D / 4) + lane];
        const f32x4 e1 = tl4[r * (D / 4) + lane + 64];

        float dot = f0.x * e0.x + f0.y * e0.y + f0.z * e0.z + f0.w * e0.w
                  + f1.x * e1.x + f1.y * e1.y + f1.z * e1.z + f1.w * e1.w;
        float fss = f0.x * f0.x + f0.y * f0.y + f0.z * f0.z + f0.w * f0.w
                  + f1.x * f1.x + f1.y * f1.y + f1.z * f1.z + f1.w * f1.w;

        #pragma unroll
        for (int off = 32; off > 0; off >>= 1) {
            dot += __shfl_xor(dot, off, 64);
            fss += __shfl_xor(fss, off, 64);
        }

        const float sim = dot * (1.0f / sqrtf(fss)) * inv_ne[r];
        const float lab = lb[r];                    // wave-uniform
        const float S = 0.5f * (1.0f + sim) + EPS_LOG;
        const float T = 1.0f
            - ((float)(C - 1) / (float)C) * fabsf(1.0f / (float)(C - 1) + sim)
            + EPS_LOG;
        // labels are exactly 0.0 or 1.0
        wacc += logf(lab > 0.5f ? S : T);
    }

    if (lane == 0) wsum[wid] = wacc;
    __syncthreads();
    if (t == 0) {
        float acc = 0.0f;
        #pragma unroll
        for (int w = 0; w < WPB; ++w) acc += wsum[w];
        partial[blockIdx.x] = acc;   // written fresh every launch
    }
}

__global__ __launch_bounds__(256) void fll_reduce(
    const float* __restrict__ partial, float* __restrict__ out)
{
    const int lane = threadIdx.x & 63;
    const int wave = threadIdx.x >> 6;
    double acc = 0.0;
    for (int i = threadIdx.x; i < NBLOCKS; i += 256) acc += (double)partial[i];

    #pragma unroll
    for (int off = 32; off > 0; off >>= 1) acc += __shfl_xor(acc, off, 64);

    __shared__ double sd[4];
    if (lane == 0) sd[wave] = acc;
    __syncthreads();
    if (threadIdx.x == 0) {
        double tot = 0.0;
        #pragma unroll
        for (int w = 0; w < 4; ++w) tot += sd[w];
        out[0] = (float)(-tot / (double)NROWS);
    }
}

extern "C" void kernel_launch(void* const* d_in, const int* in_sizes, int n_in,
                              void* d_out, int out_size, void* d_ws, size_t ws_size,
                              hipStream_t stream) {
    const float* feat   = (const float*)d_in[0];   // (B, C, D)
    const float* emb    = (const float*)d_in[1];   // (C, D)
    const float* labels = (const float*)d_in[2];   // (B, C)
    float* out = (float*)d_out;
    float* partial = (float*)d_ws;                 // NBLOCKS floats

    fll_main<<<NBLOCKS, THREADS, 0, stream>>>(feat, emb, labels, partial);
    fll_reduce<<<1, 256, 0, stream>>>(partial, out);
}

// Round 9
// 64.151 us; speedup vs baseline: 1.1260x; 1.1260x over previous
//
#include <hip/hip_runtime.h>
#include <math.h>

// FeatureLabelLoss: features (B,C,D) f32, embeddings (C,D) f32, labels (B,C) f32
// -> scalar f32 loss.  BW-bound on the 327.7 MB features stream.
//
// Lessons:
//  R2: NO per-block __threadfence (buffer_wbl2 serializes the chip).
//  R5: NO same-address global atomic hammering (+79 us for 5000 fp64 adds).
//  R6: tail/balance is NOT the limiter (tail-free grid == R1 == 65.3 us).
//  R7: contiguous streams + LDS emb tile = WORSE (72.2) -- added ds_read
//      traffic to an already ~84%-busy DS pipe.
//  => Theory: per row, HBM gives 2KB/83cyc; 12 shfl_xor (ds_swizzle) cost
//     ~70cyc on the single per-CU DS unit -> DS pipe co-limits at ~84%.
//
// R8 single variable vs R6: cross-lane reduction moved DS -> VALU via DPP
// (quad_perm xor1/xor2, row_half_mirror, row_mirror, row_bcast15/31 +
// v_readlane). Hot loop now issues ZERO DS instructions.

typedef float f32x4 __attribute__((ext_vector_type(4)));

constexpr int B = 32;
constexpr int C = 5000;
constexpr int D = 512;                 // 512 floats = 2 f32x4 per lane
constexpr int NROWS = B * C;           // 160000
constexpr float EPS_LOG = 1e-6f;

constexpr int WPB = 4;                 // waves per block
constexpr int THREADS = WPB * 64;      // 256
constexpr int NBLOCKS = 1280;          // = 5 blocks/CU exactly, all resident
constexpr int NWAVES_TOT = NBLOCKS * WPB;   // 5120
constexpr int QROWS = 8;               // rows per work unit
constexpr int UNITS = NROWS / QROWS;   // 20000 = (c, quarter) pairs

// ---- full-wave (64-lane) sum on the VALU pipe only -------------------------
template <int CTRL, int RM>
__device__ __forceinline__ float dpp_add(float x) {
    int yi = __builtin_amdgcn_update_dpp(
        __builtin_bit_cast(int, x), __builtin_bit_cast(int, x),
        CTRL, RM, 0xF, true);
    return x + __builtin_bit_cast(float, yi);
}

__device__ __forceinline__ float wave_sum_dpp(float x) {
    x = dpp_add<0xB1, 0xF>(x);   // quad_perm [1,0,3,2]  : xor 1
    x = dpp_add<0x4E, 0xF>(x);   // quad_perm [2,3,0,1]  : xor 2
    x = dpp_add<0x141, 0xF>(x);  // row_half_mirror      : pair 4<->7 etc.
    x = dpp_add<0x140, 0xF>(x);  // row_mirror           : row-of-16 sums
    x = dpp_add<0x142, 0xA>(x);  // row_bcast15, rows 1&3: row1=s0+s1, row3=s2+s3
    x = dpp_add<0x143, 0xC>(x);  // row_bcast31, rows 2&3: row3 = full sum
    return __builtin_bit_cast(float,
        __builtin_amdgcn_readlane(__builtin_bit_cast(int, x), 63));
}

__global__ __launch_bounds__(THREADS) void fll_main(
    const float* __restrict__ feat,
    const float* __restrict__ emb,
    const float* __restrict__ labels,
    float* __restrict__ partial)
{
    const int lane = threadIdx.x & 63;
    const int wid  = threadIdx.x >> 6;
    const int gw   = blockIdx.x * WPB + wid;   // 0 .. 5119

    const size_t bstr = (size_t)C * D;
    float wacc = 0.0f;   // identical across lanes of the wave

    // units u, u+5120, u+10240, u+15360  (4 or 3 per wave)
    for (int u = gw; u < UNITS; u += NWAVES_TOT) {
        const int c = u >> 2;            // consecutive waves share c -> L1 reuse
        const int q = u & 3;             // which 8-row quarter of B

        // embedding row for this c: registers, reused for 8 feature rows
        const f32x4* er = reinterpret_cast<const f32x4*>(emb + (size_t)c * D);
        const f32x4 e0 = er[lane];
        const f32x4 e1 = er[lane + 64];
        float essl = e0.x * e0.x + e0.y * e0.y + e0.z * e0.z + e0.w * e0.w
                   + e1.x * e1.x + e1.y * e1.y + e1.z * e1.z + e1.w * e1.w;
        const float ess = wave_sum_dpp(essl);

        const float* fb = feat + (size_t)(q * QROWS) * bstr + (size_t)c * D;
        const float* lb = labels + (size_t)(q * QROWS) * C + c;

        #pragma unroll 4
        for (int i = 0; i < QROWS; ++i) {
            const f32x4* fr = reinterpret_cast<const f32x4*>(fb + (size_t)i * bstr);
            const f32x4 f0 = fr[lane];
            const f32x4 f1 = fr[lane + 64];

            float dotl = f0.x * e0.x + f0.y * e0.y + f0.z * e0.z + f0.w * e0.w
                       + f1.x * e1.x + f1.y * e1.y + f1.z * e1.z + f1.w * e1.w;
            float fssl = f0.x * f0.x + f0.y * f0.y + f0.z * f0.z + f0.w * f0.w
                       + f1.x * f1.x + f1.y * f1.y + f1.z * f1.z + f1.w * f1.w;

            const float dot = wave_sum_dpp(dotl);   // VALU-only reductions
            const float fss = wave_sum_dpp(fssl);

            // norms ~sqrt(512) >> EPS_NORM -> combined form exact (validated)
            const float sim = dot / sqrtf(fss * ess);
            const float lab = lb[(size_t)i * C];    // wave-uniform
            const float S = 0.5f * (1.0f + sim) + EPS_LOG;
            const float T = 1.0f
                - ((float)(C - 1) / (float)C) * fabsf(1.0f / (float)(C - 1) + sim)
                + EPS_LOG;
            // labels are exactly 0.0 or 1.0
            wacc += logf(lab > 0.5f ? S : T);
        }
    }

    __shared__ float wsum[WPB];
    if (lane == 0) wsum[wid] = wacc;
    __syncthreads();
    if (threadIdx.x == 0) {
        float s = 0.0f;
        #pragma unroll
        for (int w = 0; w < WPB; ++w) s += wsum[w];
        partial[blockIdx.x] = s;   // written fresh every launch
    }
}

__global__ __launch_bounds__(256) void fll_reduce(
    const float* __restrict__ partial, float* __restrict__ out)
{
    const int lane = threadIdx.x & 63;
    const int wave = threadIdx.x >> 6;
    double acc = 0.0;
    for (int i = threadIdx.x; i < NBLOCKS; i += 256) acc += (double)partial[i];

    #pragma unroll
    for (int off = 32; off > 0; off >>= 1) acc += __shfl_xor(acc, off, 64);

    __shared__ double sd[4];
    if (lane == 0) sd[wave] = acc;
    __syncthreads();
    if (threadIdx.x == 0) {
        double tot = 0.0;
        #pragma unroll
        for (int w = 0; w < 4; ++w) tot += sd[w];
        out[0] = (float)(-tot / (double)NROWS);
    }
}

extern "C" void kernel_launch(void* const* d_in, const int* in_sizes, int n_in,
                              void* d_out, int out_size, void* d_ws, size_t ws_size,
                              hipStream_t stream) {
    const float* feat   = (const float*)d_in[0];   // (B, C, D)
    const float* emb    = (const float*)d_in[1];   // (C, D)
    const float* labels = (const float*)d_in[2];   // (B, C)
    float* out = (float*)d_out;
    float* partial = (float*)d_ws;                 // NBLOCKS floats

    fll_main<<<NBLOCKS, THREADS, 0, stream>>>(feat, emb, labels, partial);
    fll_reduce<<<1, 256, 0, stream>>>(partial, out);
}